// Round 9
// baseline (36.242 us; speedup 1.0000x reference)
//
#include <hip/hip_runtime.h>
#include <hip/hip_bf16.h>
#include <math.h>

#define EMBED 128
#define VOCAB 32000
#define MEMN  50
#define BATCH 16
#define NQ    10
#define SQ    20
#define SS    40
#define BN    (BATCH*NQ)   // 160
#define NHOPS 3
#define NV    64           // vocab rows per k_out block

typedef short v8s __attribute__((ext_vector_type(8)));
typedef float v4f __attribute__((ext_vector_type(4)));

__device__ __forceinline__ float posw(int j, int J, int k) {
    float jf = (float)(j + 1) / (float)J;
    return 1.0f - jf - ((float)(k + 1) / (float)EMBED) * (1.0f - 2.0f * jf);
}

__device__ __forceinline__ short f2bf(float f) {
    __hip_bfloat16 h = __float2bfloat16(f);
    return *(short*)&h;
}

// ---- Kernel 1 (R8-exact): query | story | H^T ----
__global__ void k_embed(const int* __restrict__ cq, const int* __restrict__ story,
                        const float* __restrict__ Bw, const float* __restrict__ Aw,
                        const float* __restrict__ Cw, const float* __restrict__ TA,
                        const float* __restrict__ TC, const float* __restrict__ Hw,
                        float* __restrict__ state, float* __restrict__ memb,
                        float* __restrict__ outb, float* __restrict__ HwT) {
    int blk = blockIdx.x;
    int t = threadIdx.x;   // 128
    if (blk < BN) {
        float acc = 0.f;
        #pragma unroll
        for (int s = 0; s < SQ; ++s) {
            int tok = cq[blk * SQ + s];
            acc += Bw[tok * EMBED + t] * posw(s, SQ, t);
        }
        state[blk * EMBED + t] = acc;
    } else if (blk < BN + BATCH * MEMN) {
        int br = blk - BN;
        int r = br % MEMN;
        float ma = TA[r * EMBED + t];
        float mc = TC[r * EMBED + t];
        const int* toks = story + br * SS;
        #pragma unroll 4
        for (int s = 0; s < SS; ++s) {
            int tok = toks[s];
            float w = posw(s, SS, t);
            ma += Aw[tok * EMBED + t] * w;
            mc += Cw[tok * EMBED + t] * w;
        }
        memb[br * EMBED + t] = ma;
        outb[br * EMBED + t] = mc;
    } else {
        int k = blk - (BN + BATCH * MEMN);
        HwT[k * EMBED + t] = Hw[t * EMBED + k];
    }
}

// ---- Kernel 2 v3: single-wave blocks, ZERO barriers (R7/R8 evidence:
// critical path = barrier+LDS-roundtrip phases, not FMA chains).
// 64 thr/block, one query each. Lane owns dims {l, l+64}; state in regs.
// lmem/lout XOR-swizzled (G4: lanes read different rows, same col-range).
__global__ __launch_bounds__(64) void k_hops(const float* __restrict__ memb,
                                             const float* __restrict__ outb,
                                             const float* __restrict__ Hw,
                                             const float* __restrict__ Hb,
                                             const float* __restrict__ state,
                                             __hip_bfloat16* __restrict__ stateb) {
    __shared__ float lmem[MEMN][EMBED];
    __shared__ float lout[MEMN][EMBED];
    __shared__ float lstate[EMBED];
    __shared__ float lprobs[MEMN];
    __shared__ float lresp[EMBED];
    int bn = blockIdx.x;
    int b  = bn / NQ;
    int l  = threadIdx.x;   // 64
    int d0 = l, d1 = l + 64;

    // Stage batch memories, float4, XOR-swizzled 16B slots within 128B stripes
    size_t base = (size_t)b * MEMN * EMBED;
    #pragma unroll 5
    for (int i = l; i < MEMN * EMBED / 4; i += 64) {
        int row = i >> 5, c4 = i & 31;
        int sc4 = c4 ^ (row & 7);
        *(float4*)&lmem[row][sc4 << 2] = *(const float4*)&memb[base + ((size_t)i << 2)];
        *(float4*)&lout[row][sc4 << 2] = *(const float4*)&outb[base + ((size_t)i << 2)];
    }
    float st0 = state[bn * EMBED + d0];
    float st1 = state[bn * EMBED + d1];
    lstate[d0] = st0; lstate[d1] = st1;
    float hb0 = Hb[d0], hb1 = Hb[d1];
    asm volatile("" ::: "memory");

    int r = (l < MEMN) ? l : 0;   // idle lanes alias row 0 (broadcast, harmless)
    for (int hop = 0; hop < NHOPS; ++hop) {
        // ---- logits: lane r dots its swizzled row against broadcast state ----
        float a0 = 0.f, a1 = 0.f, a2 = 0.f, a3 = 0.f;
        #pragma unroll
        for (int j = 0; j < 32; ++j) {
            float4 m = *(const float4*)&lmem[r][(j ^ (r & 7)) << 2];
            float4 s = *(const float4*)&lstate[j << 2];
            a0 += m.x * s.x; a1 += m.y * s.y; a2 += m.z * s.z; a3 += m.w * s.w;
        }
        float logit = (l < MEMN) ? (a0 + a1) + (a2 + a3) : -1e30f;
        // ---- softmax: pure wave shuffles ----
        float mx = logit;
        #pragma unroll
        for (int off = 32; off; off >>= 1) mx = fmaxf(mx, __shfl_xor(mx, off, 64));
        float e = (l < MEMN) ? __expf(logit - mx) : 0.f;
        float ss = e;
        #pragma unroll
        for (int off = 32; off; off >>= 1) ss += __shfl_xor(ss, off, 64);
        if (l < MEMN) lprobs[l] = e / ss;
        asm volatile("" ::: "memory");
        // ---- response: lane accumulates its two dims over 50 rows ----
        float r0 = 0.f, r1 = 0.f, q0 = 0.f, q1 = 0.f;
        #pragma unroll
        for (int k = 0; k < MEMN; k += 2) {
            float p0 = lprobs[k], p1 = lprobs[k + 1];
            r0 += p0 * lout[k    ][(((d0 >> 2) ^ (k & 7)) << 2)       | (d0 & 3)];
            q0 += p0 * lout[k    ][(((d1 >> 2) ^ (k & 7)) << 2)       | (d1 & 3)];
            r1 += p1 * lout[k + 1][(((d0 >> 2) ^ ((k + 1) & 7)) << 2) | (d0 & 3)];
            q1 += p1 * lout[k + 1][(((d1 >> 2) ^ ((k + 1) & 7)) << 2) | (d1 & 3)];
        }
        lresp[d0] = r0 + r1;
        lresp[d1] = q0 + q1;
        asm volatile("" ::: "memory");
        // ---- H-update: lane reads its own contiguous Hw rows (L2-hot) ----
        float h00 = hb0 + st0, h01 = 0.f, h02 = 0.f, h03 = 0.f;
        float h10 = hb1 + st1, h11 = 0.f, h12 = 0.f, h13 = 0.f;
        #pragma unroll 8
        for (int j = 0; j < 32; ++j) {
            float4 rv = *(const float4*)&lresp[j << 2];
            float4 w0 = *(const float4*)&Hw[(size_t)d0 * EMBED + (j << 2)];
            float4 w1 = *(const float4*)&Hw[(size_t)d1 * EMBED + (j << 2)];
            h00 += rv.x * w0.x; h01 += rv.y * w0.y; h02 += rv.z * w0.z; h03 += rv.w * w0.w;
            h10 += rv.x * w1.x; h11 += rv.y * w1.y; h12 += rv.z * w1.z; h13 += rv.w * w1.w;
        }
        st0 = (h00 + h01) + (h02 + h03);
        st1 = (h10 + h11) + (h12 + h13);
        if (hop < NHOPS - 1) {
            lstate[d0] = st0; lstate[d1] = st1;
            asm volatile("" ::: "memory");
        }
    }
    stateb[bn * EMBED + d0] = __float2bfloat16(st0);
    stateb[bn * EMBED + d1] = __float2bfloat16(st1);
}

// ---- Kernel 3 (R8-exact): MFMA GEMM ----
__global__ __launch_bounds__(256) void k_out(const __hip_bfloat16* __restrict__ stateb,
                                             const float* __restrict__ outw,
                                             float* __restrict__ out) {
    __shared__ __align__(16) __hip_bfloat16 Alds[BN][EMBED + 8];
    __shared__ __align__(16) __hip_bfloat16 Blds[NV][EMBED + 8];
    int t = threadIdx.x;
    int vbase = blockIdx.x * NV;

    #pragma unroll
    for (int i = 0; i < 10; ++i) {
        int e = t + i * 256;
        int row = e >> 4, c8 = (e & 15) << 3;
        *(int4*)&Alds[row][c8] = *(const int4*)&stateb[row * EMBED + c8];
    }
    #pragma unroll
    for (int i = 0; i < 8; ++i) {
        int e = t + i * 256;
        int row = e >> 5, c4 = (e & 31) << 2;
        float4 w = *(const float4*)&outw[(size_t)(vbase + row) * EMBED + c4];
        short4 p;
        p.x = f2bf(w.x); p.y = f2bf(w.y); p.z = f2bf(w.z); p.w = f2bf(w.w);
        *(short4*)&Blds[row][c4] = p;
    }
    __syncthreads();

    int wv = t >> 6;
    int l = t & 63;
    int col16 = l & 15;
    int kg = l >> 4;

    v8s bfrag[4];
    #pragma unroll
    for (int k4 = 0; k4 < 4; ++k4)
        bfrag[k4] = *(v8s*)&Blds[(wv << 4) + col16][k4 * 32 + kg * 8];

    v4f acc[10];
    #pragma unroll
    for (int m = 0; m < 10; ++m) acc[m] = (v4f){0.f, 0.f, 0.f, 0.f};

    #pragma unroll
    for (int k4 = 0; k4 < 4; ++k4) {
        #pragma unroll
        for (int m = 0; m < 10; ++m) {
            v8s af = *(v8s*)&Alds[m * 16 + col16][k4 * 32 + kg * 8];
            acc[m] = __builtin_amdgcn_mfma_f32_16x16x32_bf16(af, bfrag[k4], acc[m], 0, 0, 0);
        }
    }

    int colg = vbase + (wv << 4) + col16;
    #pragma unroll
    for (int m = 0; m < 10; ++m) {
        #pragma unroll
        for (int i = 0; i < 4; ++i) {
            out[(size_t)(m * 16 + kg * 4 + i) * VOCAB + colg] = acc[m][i];
        }
    }
}

extern "C" void kernel_launch(void* const* d_in, const int* in_sizes, int n_in,
                              void* d_out, int out_size, void* d_ws, size_t ws_size,
                              hipStream_t stream) {
    const int*   ctx_query = (const int*)  d_in[0];
    const int*   story     = (const int*)  d_in[1];
    const float* A_w       = (const float*)d_in[2];
    const float* C_w       = (const float*)d_in[3];
    const float* B_w       = (const float*)d_in[4];
    const float* H_w       = (const float*)d_in[5];
    const float* H_b       = (const float*)d_in[6];
    const float* out_w     = (const float*)d_in[7];
    const float* TA        = (const float*)d_in[8];
    const float* TC        = (const float*)d_in[9];
    float* out = (float*)d_out;

    float* ws    = (float*)d_ws;
    float* state = ws;                                   // 160*128 f32
    float* memb  = state + BN * EMBED;                   // 16*50*128
    float* outb  = memb + BATCH * MEMN * EMBED;          // 16*50*128
    float* HwT   = outb + BATCH * MEMN * EMBED;          // 128*128 (unused by hops v3)
    __hip_bfloat16* stateb = (__hip_bfloat16*)(HwT + EMBED * EMBED);  // 160*128 bf16

    k_embed<<<BN + BATCH * MEMN + EMBED, EMBED, 0, stream>>>(
        ctx_query, story, B_w, A_w, C_w, TA, TC, H_w, state, memb, outb, HwT);
    k_hops<<<BN, 64, 0, stream>>>(memb, outb, H_w, H_b, state, stateb);
    k_out<<<VOCAB / NV, 256, 0, stream>>>(stateb, out_w, out);
}